// Round 6
// baseline (1472.258 us; speedup 1.0000x reference)
//
#include <hip/hip_runtime.h>
#include <math.h>

// Laminography forward projector, fully fused pipeline:
//  (1) centered 3D FFT of complex volume (3 1D passes into d_ws)
//  (2) trilinear Fourier-slice sampling FUSED with the centered inverse FFT
//      along detector axis b -> d_out
//  (3) centered inverse FFT along detector axis a (1 pass, in place)
// Centered transform identity (n=256, n/2 even):
//  F[k] = (-1)^k * FFT[ (-1)^x * u[x] ]   per axis, forward and inverse alike.
//
// FFT structure: 256 = 16 x 16 two-phase register FFT.
//  x = n1 + 16*n2, k = k2 + 16*k1:
//  X[k2+16k1] = sum_n1 W16^{n1 k1} * [ W256^{n1 k2} * sum_n2 W16^{n2 k2} v[n1+16n2] ]
//  Phase A (thread = n1): 16-pt register FFT over n2, twiddle W256^{n1 k2}, -> LDS
//  Phase B (thread = k2): 16-pt register FFT over n1, -> global.
//  One LDS round-trip + ONE barrier per 256-pt line.

namespace {

__device__ const int BR4[16] = {0, 8, 4, 12, 2, 10, 6, 14,
                                1, 9, 5, 13, 3, 11, 7, 15};

__device__ __forceinline__ void fft16_reg(float (&re)[16], float (&im)[16],
                                          bool inv) {
  // radix-2 DIF, 16 points; input natural order, output bit-reversed.
  const float C16[8] = {1.0f, 0.92387953251128675613f, 0.70710678118654752440f,
                        0.38268343236508977173f, 0.0f, -0.38268343236508977173f,
                        -0.70710678118654752440f, -0.92387953251128675613f};
  const float S16[8] = {0.0f, 0.38268343236508977173f, 0.70710678118654752440f,
                        0.92387953251128675613f, 1.0f, 0.92387953251128675613f,
                        0.70710678118654752440f, 0.38268343236508977173f};
  #pragma unroll
  for (int s = 0; s < 4; s++) {
    const int h = 8 >> s;
    #pragma unroll
    for (int g = 0; g < (8 >> (3 - s)); g++) {
      #pragma unroll
      for (int p = 0; p < h; p++) {
        const int i = g * 2 * h + p;
        const int j = i + h;
        const float ar = re[i], ai = im[i], br = re[j], bi = im[j];
        re[i] = ar + br;
        im[i] = ai + bi;
        const float dr = ar - br, di = ai - bi;
        const int t = p << s;
        const float wr = C16[t];
        const float wi = inv ? S16[t] : -S16[t];
        re[j] = dr * wr - di * wi;
        im[j] = dr * wi + di * wr;
      }
    }
  }
}

// MODE 0: contiguous lines (stride 1), lanes run along the line.
// MODE 1: stride 256,   lanes run across 16 memory-consecutive lines.
// MODE 2: stride 65536, lanes run across 16 memory-consecutive lines.
template<int MODE, bool INV>
__global__ __launch_bounds__(256)
void fft_pass(const float2* __restrict__ in, float2* __restrict__ out) {
  __shared__ float2 zt[16 * 273];      // 34944 B -> 4 blocks/CU
  const int t  = threadIdx.x;
  const int tx = t & 15;
  const int ty = t >> 4;
  const int idA = (MODE == 0) ? tx : ty;   // n1 in phase A, k2 in phase B
  const int lin = (MODE == 0) ? ty : tx;   // line within block
  const int lineIdx = (int)blockIdx.x * 16 + lin;
  int base, stride;
  if (MODE == 0)      { base = lineIdx * 256;                            stride = 1;     }
  else if (MODE == 1) { base = (lineIdx >> 8) * 65536 + (lineIdx & 255); stride = 256;   }
  else                { base = lineIdx;                                  stride = 65536; }

  float re[16], im[16];

  // ---------------- phase A: thread = n1 ----------------
  {
    const float s1 = (idA & 1) ? -1.0f : 1.0f;     // (-1)^x pre-twiddle
    #pragma unroll
    for (int n2 = 0; n2 < 16; n2++) {
      const float2 v = in[base + (idA + 16 * n2) * stride];
      re[n2] = v.x * s1;
      im[n2] = v.y * s1;
    }
    fft16_reg(re, im, INV);
    const float TWO_PI = 6.28318530717958647692f;
    const float ang = (INV ? TWO_PI : -TWO_PI) * ((float)idA * (1.0f / 256.0f));
    float ss, cc;
    sincosf(ang, &ss, &cc);
    float wr = 1.0f, wi = 0.0f;
    #pragma unroll
    for (int k2 = 0; k2 < 16; k2++) {
      const float yr = re[BR4[k2]], yi = im[BR4[k2]];
      zt[lin * 273 + idA * 17 + k2] =
          make_float2(yr * wr - yi * wi, yr * wi + yi * wr);
      const float nwr = wr * cc - wi * ss;
      wi = wr * ss + wi * cc;
      wr = nwr;
    }
  }
  __syncthreads();
  // ---------------- phase B: thread = k2 ----------------
  {
    #pragma unroll
    for (int n1 = 0; n1 < 16; n1++) {
      const float2 z = zt[lin * 273 + n1 * 17 + idA];
      re[n1] = z.x;
      im[n1] = z.y;
    }
    fft16_reg(re, im, INV);
    const float sOut = ((idA & 1) ? -1.0f : 1.0f) * (INV ? (1.0f / 256.0f) : 1.0f);
    #pragma unroll
    for (int k1 = 0; k1 < 16; k1++) {
      out[base + (idA + 16 * k1) * stride] =
          make_float2(re[BR4[k1]] * sOut, im[BR4[k1]] * sOut);
    }
  }
}

// Fourier-slice trilinear sampling FUSED with the centered inverse FFT along
// detector axis b.  One block = one angle m x 16 a-lines x full 256 b.
// Phase A thread (tx = a-line, ty = n1): gathers the 16 pixels b = ty+16*n2
// (exactly n1=ty's FFT point set -> no redistribution needed).
// Register discipline (round-5 lesson: full unroll let the scheduler hoist
// ~128 loads -> 256 VGPR -> 8.7% occupancy -> 237us):
//  - __launch_bounds__(256,4): allocator capped at 128 VGPR (16 waves/CU,
//    matching the LDS limit of 4 blocks/CU).
//  - sched_barrier(0) between 4-iteration gather chunks: <=32 loads in
//    flight, unroll indices stay compile-time (no scratch).
__global__ __launch_bounds__(256, 4)
void sample_ifftb(const float2* __restrict__ F, float2* __restrict__ out,
                  const float* __restrict__ theta, const float* __restrict__ tiltp) {
  __shared__ float2 zt[16 * 273];
  const int t  = threadIdx.x;
  const int tx = t & 15;
  const int ty = t >> 4;
  const int m  = blockIdx.y;
  const int a  = blockIdx.x * 16 + tx;

  float th = theta[m];
  float st, ct;
  sincosf(th, &st, &ct);
  float tl = tiltp[0];
  float sp, cp;
  sincosf(tl, &sp, &cp);

  const float av = (float)(a - 128);
  // z taps: depend only on a
  const float p2 = av * sp + 128.0f;
  const float f2 = floorf(p2);
  const int   z0 = (int)f2;
  const float fz = p2 - f2;
  const int   z1 = z0 + 1;
  const float wz0 = ((z0 >= 0) && (z0 < 256)) ? (1.0f - fz) : 0.0f;
  const float wz1 = ((z1 >= 0) && (z1 < 256)) ? fz : 0.0f;
  const int  zc0 = min(max(z0, 0), 255);
  const int  zc1 = min(max(z1, 0), 255);
  const float p0b = av * (-st * cp) + 128.0f;
  const float p1b = av * (ct * cp) + 128.0f;

  float re[16], im[16];
  // ---------------- phase A: gather + 16-pt FFT over n2 ----------------
  const float s1 = (ty & 1) ? -1.0f : 1.0f;   // (-1)^b, b = ty + 16*n2
  #pragma unroll
  for (int n2c = 0; n2c < 4; n2c++) {
    #pragma unroll
    for (int n2i = 0; n2i < 4; n2i++) {
      const int n2 = n2c * 4 + n2i;
      const int b = ty + 16 * n2;
      const float bu = (float)(b - 128);
      const float p0 = bu * ct + p0b;
      const float p1 = bu * st + p1b;
      const float f0 = floorf(p0), f1 = floorf(p1);
      const int x0 = (int)f0, y0 = (int)f1;
      const float fx = p0 - f0, fy = p1 - f1;
      float accr = 0.0f, acci = 0.0f;
      #pragma unroll
      for (int dx = 0; dx < 2; dx++) {
        const int x = x0 + dx;
        const bool vx = (x >= 0) && (x < 256);
        const int xc = min(max(x, 0), 255);
        const float wx = dx ? fx : (1.0f - fx);
        #pragma unroll
        for (int dy = 0; dy < 2; dy++) {
          const int y = y0 + dy;
          const bool vy = vx && (y >= 0) && (y < 256);
          const int yc = min(max(y, 0), 255);
          const float wxy = vy ? wx * (dy ? fy : (1.0f - fy)) : 0.0f;
          const int rowbase = (xc * 256 + yc) * 256;
          const float2 c0 = F[rowbase + zc0];
          const float2 c1 = F[rowbase + zc1];
          const float w0 = wxy * wz0;
          const float w1 = wxy * wz1;
          accr += w0 * c0.x + w1 * c1.x;
          acci += w0 * c0.y + w1 * c1.y;
        }
      }
      re[n2] = accr * s1;
      im[n2] = acci * s1;
    }
    // fence the scheduler: don't hoist the next chunk's 32 loads up here
    __builtin_amdgcn_sched_barrier(0);
  }
  fft16_reg(re, im, true);
  {
    // inter-stage twiddle W256^{+n1*k2} (inverse), n1 = ty
    const float TWO_PI = 6.28318530717958647692f;
    const float ang = TWO_PI * ((float)ty * (1.0f / 256.0f));
    float ss, cc;
    sincosf(ang, &ss, &cc);
    float wr = 1.0f, wi = 0.0f;
    #pragma unroll
    for (int k2 = 0; k2 < 16; k2++) {
      const float yr = re[BR4[k2]], yi = im[BR4[k2]];
      zt[tx * 273 + ty * 17 + k2] =
          make_float2(yr * wr - yi * wi, yr * wi + yi * wr);
      const float nwr = wr * cc - wi * ss;
      wi = wr * ss + wi * cc;
      wr = nwr;
    }
  }
  __syncthreads();
  // ---------------- phase B: thread = k2 (= tx), line = ty ----------------
  {
    #pragma unroll
    for (int n1 = 0; n1 < 16; n1++) {
      const float2 z = zt[ty * 273 + n1 * 17 + tx];
      re[n1] = z.x;
      im[n1] = z.y;
    }
    fft16_reg(re, im, true);
    const float sOut = ((tx & 1) ? -1.0f : 1.0f) * (1.0f / 256.0f);
    const int aB = blockIdx.x * 16 + ty;
    const size_t base = ((size_t)m * 256 + aB) * 256;
    #pragma unroll
    for (int k1 = 0; k1 < 16; k1++) {
      out[base + tx + 16 * k1] =
          make_float2(re[BR4[k1]] * sOut, im[BR4[k1]] * sOut);
    }
  }
}

}  // namespace

extern "C" void kernel_launch(void* const* d_in, const int* in_sizes, int n_in,
                              void* d_out, int out_size, void* d_ws, size_t ws_size,
                              hipStream_t stream) {
  const float2* w  = (const float2*)d_in[0];   // (256,256,256,2) f32 == float2 complex
  const float*  th = (const float*)d_in[1];    // (180,)
  const float*  tl = (const float*)d_in[2];    // scalar
  float2* F    = (float2*)d_ws;                // 256^3 complex64 = 128 MiB
  float2* out2 = (float2*)d_out;               // (180,256,256) complex64 view of output

  // forward 3D FFT (centered), one pass per axis, 65536 lines each (16/block)
  fft_pass<0, false><<<4096, 256, 0, stream>>>(w, F);   // axis 2 (contiguous)
  fft_pass<1, false><<<4096, 256, 0, stream>>>(F, F);   // axis 1 (stride 256)
  fft_pass<2, false><<<4096, 256, 0, stream>>>(F, F);   // axis 0 (stride 65536)

  // Fourier-slice sampling fused with inverse FFT along b -> d_out
  dim3 g(16, 180);
  sample_ifftb<<<g, 256, 0, stream>>>(F, out2, th, tl);

  // centered inverse FFT along a (stride 256), in place in d_out
  fft_pass<1, true><<<2880, 256, 0, stream>>>(out2, out2);
}

// Round 7
// 541.618 us; speedup vs baseline: 2.7183x; 2.7183x over previous
//
#include <hip/hip_runtime.h>
#include <math.h>

// Laminography forward projector, fully fused pipeline:
//  (1) centered 3D FFT of complex volume (3 1D passes into d_ws)
//  (2) trilinear Fourier-slice sampling FUSED with the centered inverse FFT
//      along detector axis b -> d_out
//  (3) centered inverse FFT along detector axis a (1 pass, in place)
// Centered transform identity (n=256, n/2 even):
//  F[k] = (-1)^k * FFT[ (-1)^x * u[x] ]   per axis, forward and inverse alike.
//
// FFT structure: 256 = 16 x 16 two-phase register FFT.
//  x = n1 + 16*n2, k = k2 + 16*k1:
//  X[k2+16k1] = sum_n1 W16^{n1 k1} * [ W256^{n1 k2} * sum_n2 W16^{n2 k2} v[n1+16n2] ]
//  Phase A (thread = n1): 16-pt register FFT over n2, twiddle W256^{n1 k2}, -> LDS
//  Phase B (thread = k2): 16-pt register FFT over n1, -> global.

namespace {

__device__ const int BR4[16] = {0, 8, 4, 12, 2, 10, 6, 14,
                                1, 9, 5, 13, 3, 11, 7, 15};

__device__ __forceinline__ void fft16_reg(float (&re)[16], float (&im)[16],
                                          bool inv) {
  // radix-2 DIF, 16 points; input natural order, output bit-reversed.
  const float C16[8] = {1.0f, 0.92387953251128675613f, 0.70710678118654752440f,
                        0.38268343236508977173f, 0.0f, -0.38268343236508977173f,
                        -0.70710678118654752440f, -0.92387953251128675613f};
  const float S16[8] = {0.0f, 0.38268343236508977173f, 0.70710678118654752440f,
                        0.92387953251128675613f, 1.0f, 0.92387953251128675613f,
                        0.70710678118654752440f, 0.38268343236508977173f};
  #pragma unroll
  for (int s = 0; s < 4; s++) {
    const int h = 8 >> s;
    #pragma unroll
    for (int g = 0; g < (8 >> (3 - s)); g++) {
      #pragma unroll
      for (int p = 0; p < h; p++) {
        const int i = g * 2 * h + p;
        const int j = i + h;
        const float ar = re[i], ai = im[i], br = re[j], bi = im[j];
        re[i] = ar + br;
        im[i] = ai + bi;
        const float dr = ar - br, di = ai - bi;
        const int t = p << s;
        const float wr = C16[t];
        const float wi = inv ? S16[t] : -S16[t];
        re[j] = dr * wr - di * wi;
        im[j] = dr * wi + di * wr;
      }
    }
  }
}

// MODE 0: contiguous lines (stride 1), lanes run along the line.
// MODE 1: stride 256,   lanes run across 16 memory-consecutive lines.
// MODE 2: stride 65536, lanes run across 16 memory-consecutive lines.
template<int MODE, bool INV>
__global__ __launch_bounds__(256)
void fft_pass(const float2* __restrict__ in, float2* __restrict__ out) {
  __shared__ float2 zt[16 * 273];      // 34944 B -> 4 blocks/CU
  const int t  = threadIdx.x;
  const int tx = t & 15;
  const int ty = t >> 4;
  const int idA = (MODE == 0) ? tx : ty;   // n1 in phase A, k2 in phase B
  const int lin = (MODE == 0) ? ty : tx;   // line within block
  const int lineIdx = (int)blockIdx.x * 16 + lin;
  int base, stride;
  if (MODE == 0)      { base = lineIdx * 256;                            stride = 1;     }
  else if (MODE == 1) { base = (lineIdx >> 8) * 65536 + (lineIdx & 255); stride = 256;   }
  else                { base = lineIdx;                                  stride = 65536; }

  float re[16], im[16];

  // ---------------- phase A: thread = n1 ----------------
  {
    const float s1 = (idA & 1) ? -1.0f : 1.0f;     // (-1)^x pre-twiddle
    #pragma unroll
    for (int n2 = 0; n2 < 16; n2++) {
      const float2 v = in[base + (idA + 16 * n2) * stride];
      re[n2] = v.x * s1;
      im[n2] = v.y * s1;
    }
    fft16_reg(re, im, INV);
    const float TWO_PI = 6.28318530717958647692f;
    const float ang = (INV ? TWO_PI : -TWO_PI) * ((float)idA * (1.0f / 256.0f));
    float ss, cc;
    sincosf(ang, &ss, &cc);
    float wr = 1.0f, wi = 0.0f;
    #pragma unroll
    for (int k2 = 0; k2 < 16; k2++) {
      const float yr = re[BR4[k2]], yi = im[BR4[k2]];
      zt[lin * 273 + idA * 17 + k2] =
          make_float2(yr * wr - yi * wi, yr * wi + yi * wr);
      const float nwr = wr * cc - wi * ss;
      wi = wr * ss + wi * cc;
      wr = nwr;
    }
  }
  __syncthreads();
  // ---------------- phase B: thread = k2 ----------------
  {
    #pragma unroll
    for (int n1 = 0; n1 < 16; n1++) {
      const float2 z = zt[lin * 273 + n1 * 17 + idA];
      re[n1] = z.x;
      im[n1] = z.y;
    }
    fft16_reg(re, im, INV);
    const float sOut = ((idA & 1) ? -1.0f : 1.0f) * (INV ? (1.0f / 256.0f) : 1.0f);
    #pragma unroll
    for (int k1 = 0; k1 < 16; k1++) {
      out[base + (idA + 16 * k1) * stride] =
          make_float2(re[BR4[k1]] * sOut, im[BR4[k1]] * sOut);
    }
  }
}

// Fourier-slice trilinear sampling FUSED with the centered inverse FFT along
// detector axis b.  One block = one angle m x 16 a-lines x full 256 b.
// Phase A thread (tx = a-line, ty = n1): gathers the 16 pixels b = ty+16*n2.
//
// Register discipline (rounds 5/6 lessons):
//  - r5: keeping the 16 gather results in registers let the scheduler hoist
//    ~128 loads -> 256 VGPR -> 8.7% occupancy -> 237us.
//  - r6: capping VGPR via __launch_bounds__(256,4) made the allocator pick 64
//    and SPILL to scratch (WRITE_SIZE 92MB -> 1.5GB) -> 1134us.
//  - now: each gather result is sunk into its zt slot IMMEDIATELY (the slot
//    phase A would write anyway); __syncthreads() blocks store-to-load
//    forwarding, so gather-phase live state is ~1 iteration.  The FFT then
//    reads back its own 16 points.  sched_barrier(0) every 4 iterations
//    fences pipelining depth.  No launch-bounds min-waves.
__global__ __launch_bounds__(256)
void sample_ifftb(const float2* __restrict__ F, float2* __restrict__ out,
                  const float* __restrict__ theta, const float* __restrict__ tiltp) {
  __shared__ float2 zt[16 * 273];
  const int t  = threadIdx.x;
  const int tx = t & 15;
  const int ty = t >> 4;
  const int m  = blockIdx.y;
  const int a  = blockIdx.x * 16 + tx;

  float th = theta[m];
  float st, ct;
  sincosf(th, &st, &ct);
  float tl = tiltp[0];
  float sp, cp;
  sincosf(tl, &sp, &cp);

  const float av = (float)(a - 128);
  // z taps: depend only on a
  const float p2 = av * sp + 128.0f;
  const float f2 = floorf(p2);
  const int   z0 = (int)f2;
  const float fz = p2 - f2;
  const int   z1 = z0 + 1;
  const float wz0 = ((z0 >= 0) && (z0 < 256)) ? (1.0f - fz) : 0.0f;
  const float wz1 = ((z1 >= 0) && (z1 < 256)) ? fz : 0.0f;
  const int  zc0 = min(max(z0, 0), 255);
  const int  zc1 = min(max(z1, 0), 255);
  const float p0b = av * (-st * cp) + 128.0f;
  const float p1b = av * (ct * cp) + 128.0f;

  // ---------------- gather: results sink straight into LDS ----------------
  const float s1 = (ty & 1) ? -1.0f : 1.0f;   // (-1)^b, b = ty + 16*n2
  #pragma unroll
  for (int n2c = 0; n2c < 4; n2c++) {
    #pragma unroll
    for (int n2i = 0; n2i < 4; n2i++) {
      const int n2 = n2c * 4 + n2i;
      const int b = ty + 16 * n2;
      const float bu = (float)(b - 128);
      const float p0 = bu * ct + p0b;
      const float p1 = bu * st + p1b;
      const float f0 = floorf(p0), f1 = floorf(p1);
      const int x0 = (int)f0, y0 = (int)f1;
      const float fx = p0 - f0, fy = p1 - f1;
      float accr = 0.0f, acci = 0.0f;
      #pragma unroll
      for (int dx = 0; dx < 2; dx++) {
        const int x = x0 + dx;
        const bool vx = (x >= 0) && (x < 256);
        const int xc = min(max(x, 0), 255);
        const float wx = dx ? fx : (1.0f - fx);
        #pragma unroll
        for (int dy = 0; dy < 2; dy++) {
          const int y = y0 + dy;
          const bool vy = vx && (y >= 0) && (y < 256);
          const int yc = min(max(y, 0), 255);
          const float wxy = vy ? wx * (dy ? fy : (1.0f - fy)) : 0.0f;
          const int rowbase = (xc * 256 + yc) * 256;
          const float2 c0 = F[rowbase + zc0];
          const float2 c1 = F[rowbase + zc1];
          const float w0 = wxy * wz0;
          const float w1 = wxy * wz1;
          accr += w0 * c0.x + w1 * c1.x;
          acci += w0 * c0.y + w1 * c1.y;
        }
      }
      zt[tx * 273 + ty * 17 + n2] = make_float2(accr * s1, acci * s1);
    }
    // fence the scheduler: bound load-hoisting depth to one 4-iter chunk
    __builtin_amdgcn_sched_barrier(0);
  }
  __syncthreads();   // also defeats store->load forwarding of zt slots

  // ---------------- phase A: read own points back, FFT, twiddle ------------
  float re[16], im[16];
  #pragma unroll
  for (int n2 = 0; n2 < 16; n2++) {
    const float2 v = zt[tx * 273 + ty * 17 + n2];
    re[n2] = v.x;
    im[n2] = v.y;
  }
  fft16_reg(re, im, true);
  {
    // inter-stage twiddle W256^{+n1*k2} (inverse), n1 = ty
    const float TWO_PI = 6.28318530717958647692f;
    const float ang = TWO_PI * ((float)ty * (1.0f / 256.0f));
    float ss, cc;
    sincosf(ang, &ss, &cc);
    float wr = 1.0f, wi = 0.0f;
    #pragma unroll
    for (int k2 = 0; k2 < 16; k2++) {
      const float yr = re[BR4[k2]], yi = im[BR4[k2]];
      // overwrite own slots; no other thread touches them until after the
      // next barrier, so no extra sync needed here
      zt[tx * 273 + ty * 17 + k2] =
          make_float2(yr * wr - yi * wi, yr * wi + yi * wr);
      const float nwr = wr * cc - wi * ss;
      wi = wr * ss + wi * cc;
      wr = nwr;
    }
  }
  __syncthreads();
  // ---------------- phase B: thread = k2 (= tx), line = ty ----------------
  {
    #pragma unroll
    for (int n1 = 0; n1 < 16; n1++) {
      const float2 z = zt[ty * 273 + n1 * 17 + tx];
      re[n1] = z.x;
      im[n1] = z.y;
    }
    fft16_reg(re, im, true);
    const float sOut = ((tx & 1) ? -1.0f : 1.0f) * (1.0f / 256.0f);
    const int aB = blockIdx.x * 16 + ty;
    const size_t base = ((size_t)m * 256 + aB) * 256;
    #pragma unroll
    for (int k1 = 0; k1 < 16; k1++) {
      out[base + tx + 16 * k1] =
          make_float2(re[BR4[k1]] * sOut, im[BR4[k1]] * sOut);
    }
  }
}

}  // namespace

extern "C" void kernel_launch(void* const* d_in, const int* in_sizes, int n_in,
                              void* d_out, int out_size, void* d_ws, size_t ws_size,
                              hipStream_t stream) {
  const float2* w  = (const float2*)d_in[0];   // (256,256,256,2) f32 == float2 complex
  const float*  th = (const float*)d_in[1];    // (180,)
  const float*  tl = (const float*)d_in[2];    // scalar
  float2* F    = (float2*)d_ws;                // 256^3 complex64 = 128 MiB
  float2* out2 = (float2*)d_out;               // (180,256,256) complex64 view of output

  // forward 3D FFT (centered), one pass per axis, 65536 lines each (16/block)
  fft_pass<0, false><<<4096, 256, 0, stream>>>(w, F);   // axis 2 (contiguous)
  fft_pass<1, false><<<4096, 256, 0, stream>>>(F, F);   // axis 1 (stride 256)
  fft_pass<2, false><<<4096, 256, 0, stream>>>(F, F);   // axis 0 (stride 65536)

  // Fourier-slice sampling fused with inverse FFT along b -> d_out
  dim3 g(16, 180);
  sample_ifftb<<<g, 256, 0, stream>>>(F, out2, th, tl);

  // centered inverse FFT along a (stride 256), in place in d_out
  fft_pass<1, true><<<2880, 256, 0, stream>>>(out2, out2);
}